// Round 6
// baseline (946.728 us; speedup 1.0000x reference)
//
#include <hip/hip_runtime.h>
#include <hip/hip_bf16.h>

#define NF 128
#define RBF 20

using short8 = __attribute__((ext_vector_type(8))) short;
using f32x4  = __attribute__((ext_vector_type(4))) float;

__device__ __forceinline__ float sspf(float v) {
    return fmaxf(v, 0.f) + log1pf(__expf(-fabsf(v))) - 0.69314718055994531f;
}
__device__ __forceinline__ unsigned short f2bf(float f) {
    union { float f; unsigned u; } v; v.f = f;
    unsigned r = v.u + 0x7fffu + ((v.u >> 16) & 1u);
    return (unsigned short)(r >> 16);
}
__device__ __forceinline__ float bf2f(unsigned short s) {
    union { unsigned u; float f; } v; v.u = ((unsigned)s) << 16;
    return v.f;
}

// ---------------------------------------------------------------------------
// Edge kernel (persistent): per 64-edge tile
//   phase1 (MFMA): h = ssp(f @ W1 + b1), f bf16 LDS (K padded 20->32)
//   phase2 (MFMA): wij = h @ W2 + b2
//   phase3: gather bf16 xf/yf + fp32 atomic scatter
// Weight fragments loaded ONCE per block.
// ---------------------------------------------------------------------------
__global__ __launch_bounds__(256, 2)
void edge_mfma_kernel(const float* __restrict__ f_ij,
                      const float* __restrict__ rcut,
                      const int* __restrict__ idx_i,
                      const int* __restrict__ idx_j,
                      const float* __restrict__ Wf1,
                      const float* __restrict__ bf1,
                      const float* __restrict__ Wf2,
                      const float* __restrict__ bf2v,
                      const unsigned short* __restrict__ xf,
                      const unsigned short* __restrict__ yf,
                      float* __restrict__ conv_x,
                      float* __restrict__ conv_y,
                      int E, int nTiles)
{
    const int tid = threadIdx.x;
    const int l = tid & 63, w = tid >> 6;
    const int lr = l & 15, lk = l >> 4;
    const int wcol0 = w * 32;

    __shared__ unsigned short f16[64 * 32];   // 4 KB, [edge][k] bf16, k>=20 zero
    __shared__ unsigned short Ash[64 * NF];   // 16 KB, swizzled h
    __shared__ int io_s[64], jo_s[64];        // pre-multiplied row offsets
    __shared__ float rc_s[64];

    // persistent weight fragments
    short8 b2fr[4][2];
    #pragma unroll
    for (int kb = 0; kb < 4; ++kb)
        #pragma unroll
        for (int cb = 0; cb < 2; ++cb) {
            const int col = wcol0 + cb * 16 + lr;
            #pragma unroll
            for (int j = 0; j < 8; ++j)
                b2fr[kb][cb][j] = (short)f2bf(Wf2[(size_t)(kb * 32 + lk * 8 + j) * NF + col]);
        }
    short8 b1fr[2];
    #pragma unroll
    for (int cb = 0; cb < 2; ++cb) {
        const int col = wcol0 + cb * 16 + lr;
        #pragma unroll
        for (int j = 0; j < 8; ++j) {
            const int k = lk * 8 + j;
            b1fr[cb][j] = (k < RBF) ? (short)f2bf(Wf1[k * NF + col]) : (short)0;
        }
    }
    const float b1c0 = bf1[wcol0 + lr],      b1c1 = bf1[wcol0 + 16 + lr];
    const float b2c0 = bf2v[wcol0 + lr],     b2c1 = bf2v[wcol0 + 16 + lr];

    for (int tile = blockIdx.x; tile < nTiles; tile += gridDim.x) {
        const int e0 = tile * 64;
        __syncthreads();                      // prev-tile LDS readers done
        // stage f tile -> bf16 (zero-padded K), coalesced
        #pragma unroll
        for (int s = 0; s < 8; ++s) {
            const int t = s * 256 + tid;
            const int row = t >> 5, k = t & 31;
            float v = 0.f;
            if (k < RBF && e0 + row < E) v = f_ij[(size_t)(e0 + row) * RBF + k];
            f16[t] = f2bf(v);
        }
        if (tid < 64) {
            const int e = min(e0 + tid, E - 1);
            io_s[tid] = idx_i[e] * NF;
            jo_s[tid] = idx_j[e] * NF;
            rc_s[tid] = rcut[e];
        }
        __syncthreads();

        // phase 1: h = ssp(f @ W1 + b1), one K=32 MFMA step
        f32x4 acc1[4][2] = {};
        #pragma unroll
        for (int rb = 0; rb < 4; ++rb) {
            const short8 a = *reinterpret_cast<const short8*>(&f16[(rb * 16 + lr) * 32 + lk * 8]);
            acc1[rb][0] = __builtin_amdgcn_mfma_f32_16x16x32_bf16(a, b1fr[0], acc1[rb][0], 0, 0, 0);
            acc1[rb][1] = __builtin_amdgcn_mfma_f32_16x16x32_bf16(a, b1fr[1], acc1[rb][1], 0, 0, 0);
        }
        #pragma unroll
        for (int rb = 0; rb < 4; ++rb)
            #pragma unroll
            for (int cb = 0; cb < 2; ++cb) {
                const int col = wcol0 + cb * 16 + lr;
                #pragma unroll
                for (int q = 0; q < 4; ++q) {
                    const int e = rb * 16 + lk * 4 + q;
                    const float hv = sspf(acc1[rb][cb][q] + (cb ? b1c1 : b1c0));
                    Ash[e * NF + (col ^ ((e & 7) << 3))] = f2bf(hv);
                }
            }
        __syncthreads();

        // phase 2: wij = h @ W2 (+b2 in epilogue)
        f32x4 acc[4][2] = {};
        #pragma unroll
        for (int rb = 0; rb < 4; ++rb) {
            short8 a[4];
            #pragma unroll
            for (int kb = 0; kb < 4; ++kb) {
                const int e  = rb * 16 + lr;
                const int k0 = kb * 32 + lk * 8;
                a[kb] = *reinterpret_cast<const short8*>(&Ash[e * NF + (k0 ^ ((e & 7) << 3))]);
            }
            #pragma unroll
            for (int cb = 0; cb < 2; ++cb)
                #pragma unroll
                for (int kb = 0; kb < 4; ++kb)
                    acc[rb][cb] = __builtin_amdgcn_mfma_f32_16x16x32_bf16(
                        a[kb], b2fr[kb][cb], acc[rb][cb], 0, 0, 0);
        }

        // phase 3: gather + atomic scatter
        #pragma unroll
        for (int rb = 0; rb < 4; ++rb)
            #pragma unroll
            for (int cb = 0; cb < 2; ++cb) {
                const int col = wcol0 + cb * 16 + lr;
                const float bb = cb ? b2c1 : b2c0;
                #pragma unroll
                for (int q = 0; q < 4; ++q) {
                    const int e = rb * 16 + lk * 4 + q;
                    if (e0 + e < E) {
                        const float wv = (acc[rb][cb][q] + bb) * rc_s[e];
                        const int io = io_s[e], jo = jo_s[e];
                        const float ga = bf2f(yf[(size_t)jo + col]);
                        const float gb = bf2f(xf[(size_t)io + col]);
                        unsafeAtomicAdd(&conv_x[(size_t)io + col], ga * wv);
                        unsafeAtomicAdd(&conv_y[(size_t)jo + col], gb * wv);
                    }
                }
            }
    }
}

// ---------------------------------------------------------------------------
// Projection (persistent): out_bf16 = in @ W (bias-free), single bf16 A
// ---------------------------------------------------------------------------
__global__ __launch_bounds__(256, 2)
void proj_mfma_kernel(const float* in0, const float* in1,
                      const float* __restrict__ W0, const float* __restrict__ W1p,
                      unsigned short* o0, unsigned short* o1, int N, int nTiles)
{
    const float* in = blockIdx.y ? in1 : in0;
    const float* W  = blockIdx.y ? W1p : W0;
    unsigned short* out = blockIdx.y ? o1 : o0;

    const int tid = threadIdx.x;
    const int l = tid & 63, w = tid >> 6;
    const int lr = l & 15, lk = l >> 4;
    const int wcol0 = w * 32;

    __shared__ unsigned short Ahi[64 * NF];

    short8 bfr[4][2];
    #pragma unroll
    for (int kb = 0; kb < 4; ++kb)
        #pragma unroll
        for (int cb = 0; cb < 2; ++cb) {
            const int col = wcol0 + cb * 16 + lr;
            #pragma unroll
            for (int j = 0; j < 8; ++j)
                bfr[kb][cb][j] = (short)f2bf(W[(size_t)(kb * 32 + lk * 8 + j) * NF + col]);
        }

    for (int tile = blockIdx.x; tile < nTiles; tile += gridDim.x) {
        const int n0 = tile * 64;
        __syncthreads();
        #pragma unroll
        for (int s = 0; s < 32; ++s) {
            const int t = s * 256 + tid;
            const int row = t >> 7, cc = t & (NF - 1);
            const float v = (n0 + row < N) ? in[(size_t)(n0 + row) * NF + cc] : 0.f;
            Ahi[row * NF + (cc ^ ((row & 7) << 3))] = f2bf(v);
        }
        __syncthreads();

        f32x4 acc[4][2] = {};
        #pragma unroll
        for (int rb = 0; rb < 4; ++rb) {
            short8 a[4];
            #pragma unroll
            for (int kb = 0; kb < 4; ++kb) {
                const int e  = rb * 16 + lr;
                const int k0 = kb * 32 + lk * 8;
                a[kb] = *reinterpret_cast<const short8*>(&Ahi[e * NF + (k0 ^ ((e & 7) << 3))]);
            }
            #pragma unroll
            for (int cb = 0; cb < 2; ++cb)
                #pragma unroll
                for (int kb = 0; kb < 4; ++kb)
                    acc[rb][cb] = __builtin_amdgcn_mfma_f32_16x16x32_bf16(
                        a[kb], bfr[kb][cb], acc[rb][cb], 0, 0, 0);
        }

        #pragma unroll
        for (int rb = 0; rb < 4; ++rb)
            #pragma unroll
            for (int cb = 0; cb < 2; ++cb) {
                const int col = wcol0 + cb * 16 + lr;
                #pragma unroll
                for (int q = 0; q < 4; ++q) {
                    const int n = n0 + rb * 16 + lk * 4 + q;
                    if (n < N) out[(size_t)n * NF + col] = f2bf(acc[rb][cb][q]);
                }
            }
    }
}

// ---------------------------------------------------------------------------
// Fused output MLP (persistent): out = ssp(conv @ W1 + b1) @ W2 + b2
// conv and h both split-bf16 (hi/lo) for near-fp32 A precision.
// ---------------------------------------------------------------------------
__global__ __launch_bounds__(256, 2)
void out_fused_kernel(const float* conv0, const float* conv1,
                      const float* __restrict__ W10, const float* __restrict__ W11,
                      const float* __restrict__ b10, const float* __restrict__ b11,
                      const float* __restrict__ W20, const float* __restrict__ W21,
                      const float* __restrict__ b20, const float* __restrict__ b21,
                      float* o0, float* o1, int N, int nTiles)
{
    const float* in = blockIdx.y ? conv1 : conv0;
    const float* W1 = blockIdx.y ? W11 : W10;
    const float* b1 = blockIdx.y ? b11 : b10;
    const float* W2 = blockIdx.y ? W21 : W20;
    const float* b2 = blockIdx.y ? b21 : b20;
    float* out      = blockIdx.y ? o1  : o0;

    const int tid = threadIdx.x;
    const int l = tid & 63, w = tid >> 6;
    const int lr = l & 15, lk = l >> 4;
    const int wcol0 = w * 32;

    __shared__ unsigned short Ahi[64 * NF];
    __shared__ unsigned short Alo[64 * NF];

    short8 w1fr[4][2], w2fr[4][2];
    #pragma unroll
    for (int kb = 0; kb < 4; ++kb)
        #pragma unroll
        for (int cb = 0; cb < 2; ++cb) {
            const int col = wcol0 + cb * 16 + lr;
            #pragma unroll
            for (int j = 0; j < 8; ++j) {
                const size_t kk = (size_t)(kb * 32 + lk * 8 + j) * NF + col;
                w1fr[kb][cb][j] = (short)f2bf(W1[kk]);
                w2fr[kb][cb][j] = (short)f2bf(W2[kk]);
            }
        }
    const float b1c0 = b1[wcol0 + lr], b1c1 = b1[wcol0 + 16 + lr];
    const float b2c0 = b2[wcol0 + lr], b2c1 = b2[wcol0 + 16 + lr];

    for (int tile = blockIdx.x; tile < nTiles; tile += gridDim.x) {
        const int n0 = tile * 64;
        __syncthreads();
        #pragma unroll
        for (int s = 0; s < 32; ++s) {
            const int t = s * 256 + tid;
            const int row = t >> 7, cc = t & (NF - 1);
            const float v = (n0 + row < N) ? in[(size_t)(n0 + row) * NF + cc] : 0.f;
            const unsigned short hi = f2bf(v);
            const int idx = row * NF + (cc ^ ((row & 7) << 3));
            Ahi[idx] = hi;
            Alo[idx] = f2bf(v - bf2f(hi));
        }
        __syncthreads();

        // GEMM1 (split A)
        f32x4 acc1[4][2] = {};
        #pragma unroll
        for (int rb = 0; rb < 4; ++rb) {
            short8 ah[4], al[4];
            #pragma unroll
            for (int kb = 0; kb < 4; ++kb) {
                const int e  = rb * 16 + lr;
                const int k0 = kb * 32 + lk * 8;
                const int idx = e * NF + (k0 ^ ((e & 7) << 3));
                ah[kb] = *reinterpret_cast<const short8*>(&Ahi[idx]);
                al[kb] = *reinterpret_cast<const short8*>(&Alo[idx]);
            }
            #pragma unroll
            for (int cb = 0; cb < 2; ++cb)
                #pragma unroll
                for (int kb = 0; kb < 4; ++kb) {
                    acc1[rb][cb] = __builtin_amdgcn_mfma_f32_16x16x32_bf16(
                        ah[kb], w1fr[kb][cb], acc1[rb][cb], 0, 0, 0);
                    acc1[rb][cb] = __builtin_amdgcn_mfma_f32_16x16x32_bf16(
                        al[kb], w1fr[kb][cb], acc1[rb][cb], 0, 0, 0);
                }
        }
        __syncthreads();                       // all reads of Ahi/Alo done

        // h = ssp(acc1 + b1) -> split bf16 back into Ahi/Alo
        #pragma unroll
        for (int rb = 0; rb < 4; ++rb)
            #pragma unroll
            for (int cb = 0; cb < 2; ++cb) {
                const int col = wcol0 + cb * 16 + lr;
                #pragma unroll
                for (int q = 0; q < 4; ++q) {
                    const int e = rb * 16 + lk * 4 + q;
                    const float hv = sspf(acc1[rb][cb][q] + (cb ? b1c1 : b1c0));
                    const unsigned short hi = f2bf(hv);
                    const int idx = e * NF + (col ^ ((e & 7) << 3));
                    Ahi[idx] = hi;
                    Alo[idx] = f2bf(hv - bf2f(hi));
                }
            }
        __syncthreads();

        // GEMM2 (split A)
        f32x4 acc2[4][2] = {};
        #pragma unroll
        for (int rb = 0; rb < 4; ++rb) {
            short8 ah[4], al[4];
            #pragma unroll
            for (int kb = 0; kb < 4; ++kb) {
                const int e  = rb * 16 + lr;
                const int k0 = kb * 32 + lk * 8;
                const int idx = e * NF + (k0 ^ ((e & 7) << 3));
                ah[kb] = *reinterpret_cast<const short8*>(&Ahi[idx]);
                al[kb] = *reinterpret_cast<const short8*>(&Alo[idx]);
            }
            #pragma unroll
            for (int cb = 0; cb < 2; ++cb)
                #pragma unroll
                for (int kb = 0; kb < 4; ++kb) {
                    acc2[rb][cb] = __builtin_amdgcn_mfma_f32_16x16x32_bf16(
                        ah[kb], w2fr[kb][cb], acc2[rb][cb], 0, 0, 0);
                    acc2[rb][cb] = __builtin_amdgcn_mfma_f32_16x16x32_bf16(
                        al[kb], w2fr[kb][cb], acc2[rb][cb], 0, 0, 0);
                }
        }

        #pragma unroll
        for (int rb = 0; rb < 4; ++rb)
            #pragma unroll
            for (int cb = 0; cb < 2; ++cb) {
                const int col = wcol0 + cb * 16 + lr;
                #pragma unroll
                for (int q = 0; q < 4; ++q) {
                    const int n = n0 + rb * 16 + lk * 4 + q;
                    if (n < N)
                        out[(size_t)n * NF + col] = acc2[rb][cb][q] + (cb ? b2c1 : b2c0);
                }
            }
    }
}

extern "C" void kernel_launch(void* const* d_in, const int* in_sizes, int n_in,
                              void* d_out, int out_size, void* d_ws, size_t ws_size,
                              hipStream_t stream)
{
    const float* x    = (const float*)d_in[0];
    const float* y    = (const float*)d_in[1];
    const float* f_ij = (const float*)d_in[2];
    const float* rcut = (const float*)d_in[3];
    const int* idx_i  = (const int*)d_in[4];
    const int* idx_j  = (const int*)d_in[5];
    const float* W_in2f   = (const float*)d_in[6];
    const float* W_in2f_y = (const float*)d_in[7];
    const float* Wf1 = (const float*)d_in[8];
    const float* bf1 = (const float*)d_in[9];
    const float* Wf2 = (const float*)d_in[10];
    const float* bf2 = (const float*)d_in[11];
    const float* Wx1 = (const float*)d_in[12];
    const float* bx1 = (const float*)d_in[13];
    const float* Wx2 = (const float*)d_in[14];
    const float* bx2 = (const float*)d_in[15];
    const float* Wy1 = (const float*)d_in[16];
    const float* by1 = (const float*)d_in[17];
    const float* Wy2 = (const float*)d_in[18];
    const float* by2 = (const float*)d_in[19];

    const int N = in_sizes[0] / NF;
    const int E = in_sizes[4];

    // d_out staging: xf/yf (bf16) until edge kernel done; then final fp32 out.
    unsigned short* xf = (unsigned short*)d_out;
    unsigned short* yf = xf + (size_t)N * NF;
    float* ox = (float*)d_out;
    float* oy = ox + (size_t)N * NF;

    float* conv_x = (float*)d_ws;
    float* conv_y = conv_x + (size_t)N * NF;

    hipMemsetAsync(conv_x, 0, (size_t)2 * N * NF * sizeof(float), stream);

    const int nodeTiles = (N + 63) / 64;
    const int edgeTiles = (E + 63) / 64;

    proj_mfma_kernel<<<dim3(392, 2), 256, 0, stream>>>(
        x, y, W_in2f, W_in2f_y, xf, yf, N, nodeTiles);

    edge_mfma_kernel<<<dim3(1536), 256, 0, stream>>>(
        f_ij, rcut, idx_i, idx_j, Wf1, bf1, Wf2, bf2, xf, yf,
        conv_x, conv_y, E, edgeTiles);

    out_fused_kernel<<<dim3(392, 2), 256, 0, stream>>>(
        conv_x, conv_y, Wx1, Wy1, bx1, by1, Wx2, Wy2, bx2, by2,
        ox, oy, N, nodeTiles);
}

// Round 7
// 801.268 us; speedup vs baseline: 1.1815x; 1.1815x over previous
//
#include <hip/hip_runtime.h>
#include <hip/hip_bf16.h>

#define NF 128
#define RBF 20

using short8 = __attribute__((ext_vector_type(8))) short;
using f32x4  = __attribute__((ext_vector_type(4))) float;

__device__ __forceinline__ float sspf(float v) {
    return fmaxf(v, 0.f) + log1pf(__expf(-fabsf(v))) - 0.69314718055994531f;
}
__device__ __forceinline__ unsigned short f2bf(float f) {
    union { float f; unsigned u; } v; v.f = f;
    unsigned r = v.u + 0x7fffu + ((v.u >> 16) & 1u);
    return (unsigned short)(r >> 16);
}
__device__ __forceinline__ float bf2f(unsigned short s) {
    union { unsigned u; float f; } v; v.u = ((unsigned)s) << 16;
    return v.f;
}

// ---------------------------------------------------------------------------
// Edge kernel (persistent, 512 threads = 8 waves, 16 cols/wave):
//   phase1 (MFMA): h = ssp(f @ W1 + b1)   (K padded 20->32)
//   phase2 (MFMA): wij = h @ W2 + b2
//   phase3: gather bf16 xf/yf + fp32 atomic scatter
// Small per-wave register state (b-frags 20 VGPR) -> high occupancy to hide
// gather/atomic latency.
// ---------------------------------------------------------------------------
__global__ __launch_bounds__(512, 4)
void edge_mfma_kernel(const float* __restrict__ f_ij,
                      const float* __restrict__ rcut,
                      const int* __restrict__ idx_i,
                      const int* __restrict__ idx_j,
                      const float* __restrict__ Wf1,
                      const float* __restrict__ bf1,
                      const float* __restrict__ Wf2,
                      const float* __restrict__ bf2v,
                      const unsigned short* __restrict__ xf,
                      const unsigned short* __restrict__ yf,
                      float* __restrict__ conv_x,
                      float* __restrict__ conv_y,
                      int E, int nTiles)
{
    const int tid = threadIdx.x;
    const int l = tid & 63, w = tid >> 6;       // 8 waves
    const int lr = l & 15, lk = l >> 4;
    const int wcol = w * 16 + lr;               // this thread's output column

    __shared__ unsigned short f16[64 * 32];     // 4 KB
    __shared__ unsigned short Ash[64 * NF];     // 16 KB (swizzled h)
    __shared__ int io_s[64], jo_s[64];
    __shared__ float rc_s[64];

    // persistent weight fragments (per wave: 16 cols)
    short8 b1fr;
    #pragma unroll
    for (int j = 0; j < 8; ++j) {
        const int k = lk * 8 + j;
        b1fr[j] = (k < RBF) ? (short)f2bf(Wf1[k * NF + wcol]) : (short)0;
    }
    short8 b2fr[4];
    #pragma unroll
    for (int kb = 0; kb < 4; ++kb)
        #pragma unroll
        for (int j = 0; j < 8; ++j)
            b2fr[kb][j] = (short)f2bf(Wf2[(size_t)(kb * 32 + lk * 8 + j) * NF + wcol]);
    const float b1c = bf1[wcol];
    const float b2c = bf2v[wcol];

    for (int tile = blockIdx.x; tile < nTiles; tile += gridDim.x) {
        const int e0 = tile * 64;
        __syncthreads();                        // prev-tile LDS readers done
        #pragma unroll
        for (int s = 0; s < 4; ++s) {           // 2048 elems / 512 thr
            const int t = s * 512 + tid;
            const int row = t >> 5, k = t & 31;
            float v = 0.f;
            if (k < RBF && e0 + row < E) v = f_ij[(size_t)(e0 + row) * RBF + k];
            f16[t] = f2bf(v);
        }
        if (tid < 64) {
            const int e = min(e0 + tid, E - 1);
            io_s[tid] = idx_i[e] * NF;
            jo_s[tid] = idx_j[e] * NF;
            rc_s[tid] = rcut[e];
        }
        __syncthreads();

        // phase 1: h = ssp(f @ W1 + b1)
        f32x4 acc1[4] = {};
        #pragma unroll
        for (int rb = 0; rb < 4; ++rb) {
            const short8 a = *reinterpret_cast<const short8*>(
                &f16[(rb * 16 + lr) * 32 + lk * 8]);
            acc1[rb] = __builtin_amdgcn_mfma_f32_16x16x32_bf16(a, b1fr, acc1[rb], 0, 0, 0);
        }
        #pragma unroll
        for (int rb = 0; rb < 4; ++rb)
            #pragma unroll
            for (int q = 0; q < 4; ++q) {
                const int e = rb * 16 + lk * 4 + q;
                const float hv = sspf(acc1[rb][q] + b1c);
                Ash[e * NF + (wcol ^ ((e & 7) << 3))] = f2bf(hv);
            }
        __syncthreads();

        // phase 2: wij = h @ W2
        f32x4 acc[4] = {};
        #pragma unroll
        for (int rb = 0; rb < 4; ++rb) {
            short8 a[4];
            #pragma unroll
            for (int kb = 0; kb < 4; ++kb) {
                const int e  = rb * 16 + lr;
                const int k0 = kb * 32 + lk * 8;
                a[kb] = *reinterpret_cast<const short8*>(
                    &Ash[e * NF + (k0 ^ ((e & 7) << 3))]);
            }
            #pragma unroll
            for (int kb = 0; kb < 4; ++kb)
                acc[rb] = __builtin_amdgcn_mfma_f32_16x16x32_bf16(
                    a[kb], b2fr[kb], acc[rb], 0, 0, 0);
        }

        // phase 3: gather + atomic scatter
        #pragma unroll
        for (int rb = 0; rb < 4; ++rb)
            #pragma unroll
            for (int q = 0; q < 4; ++q) {
                const int e = rb * 16 + lk * 4 + q;
                if (e0 + e < E) {
                    const float wv = (acc[rb][q] + b2c) * rc_s[e];
                    const int io = io_s[e], jo = jo_s[e];
                    const float ga = bf2f(yf[(size_t)jo + wcol]);
                    const float gb = bf2f(xf[(size_t)io + wcol]);
                    unsafeAtomicAdd(&conv_x[(size_t)io + wcol], ga * wv);
                    unsafeAtomicAdd(&conv_y[(size_t)jo + wcol], gb * wv);
                }
            }
    }
}

// ---------------------------------------------------------------------------
// Projection (persistent): out_bf16 = in @ W (bias-free) + zero conv buffer
// ---------------------------------------------------------------------------
__global__ __launch_bounds__(256, 2)
void proj_mfma_kernel(const float* in0, const float* in1,
                      const float* __restrict__ W0, const float* __restrict__ W1p,
                      unsigned short* o0, unsigned short* o1,
                      float* convz0, float* convz1, int N, int nTiles)
{
    const float* in = blockIdx.y ? in1 : in0;
    const float* W  = blockIdx.y ? W1p : W0;
    unsigned short* out = blockIdx.y ? o1 : o0;
    float* convz        = blockIdx.y ? convz1 : convz0;

    const int tid = threadIdx.x;
    const int l = tid & 63, w = tid >> 6;
    const int lr = l & 15, lk = l >> 4;
    const int wcol0 = w * 32;

    __shared__ unsigned short Ahi[64 * NF];

    short8 bfr[4][2];
    #pragma unroll
    for (int kb = 0; kb < 4; ++kb)
        #pragma unroll
        for (int cb = 0; cb < 2; ++cb) {
            const int col = wcol0 + cb * 16 + lr;
            #pragma unroll
            for (int j = 0; j < 8; ++j)
                bfr[kb][cb][j] = (short)f2bf(W[(size_t)(kb * 32 + lk * 8 + j) * NF + col]);
        }

    for (int tile = blockIdx.x; tile < nTiles; tile += gridDim.x) {
        const int n0 = tile * 64;
        __syncthreads();
        #pragma unroll
        for (int s = 0; s < 32; ++s) {
            const int t = s * 256 + tid;
            const int row = t >> 7, cc = t & (NF - 1);
            const float v = (n0 + row < N) ? in[(size_t)(n0 + row) * NF + cc] : 0.f;
            Ahi[row * NF + (cc ^ ((row & 7) << 3))] = f2bf(v);
        }
        // zero conv rows of this tile (replaces memset, overlaps with LDS wait)
        {
            const float4 z = {0.f, 0.f, 0.f, 0.f};
            const size_t base = (size_t)n0 * NF;
            const size_t lim  = (size_t)N * NF;
            #pragma unroll
            for (int s = 0; s < 8; ++s) {
                const size_t off = base + (size_t)(s * 256 + tid) * 4;
                if (off < lim) *reinterpret_cast<float4*>(&convz[off]) = z;
            }
        }
        __syncthreads();

        f32x4 acc[4][2] = {};
        #pragma unroll
        for (int rb = 0; rb < 4; ++rb) {
            short8 a[4];
            #pragma unroll
            for (int kb = 0; kb < 4; ++kb) {
                const int e  = rb * 16 + lr;
                const int k0 = kb * 32 + lk * 8;
                a[kb] = *reinterpret_cast<const short8*>(&Ahi[e * NF + (k0 ^ ((e & 7) << 3))]);
            }
            #pragma unroll
            for (int cb = 0; cb < 2; ++cb)
                #pragma unroll
                for (int kb = 0; kb < 4; ++kb)
                    acc[rb][cb] = __builtin_amdgcn_mfma_f32_16x16x32_bf16(
                        a[kb], bfr[kb][cb], acc[rb][cb], 0, 0, 0);
        }

        #pragma unroll
        for (int rb = 0; rb < 4; ++rb)
            #pragma unroll
            for (int cb = 0; cb < 2; ++cb) {
                const int col = wcol0 + cb * 16 + lr;
                #pragma unroll
                for (int q = 0; q < 4; ++q) {
                    const int n = n0 + rb * 16 + lk * 4 + q;
                    if (n < N) out[(size_t)n * NF + col] = f2bf(acc[rb][cb][q]);
                }
            }
    }
}

// ---------------------------------------------------------------------------
// Fused output MLP (persistent): out = ssp(conv @ W1 + b1) @ W2 + b2
// conv and h both split-bf16 (hi/lo) for near-fp32 A precision.
// ---------------------------------------------------------------------------
__global__ __launch_bounds__(256, 2)
void out_fused_kernel(const float* conv0, const float* conv1,
                      const float* __restrict__ W10, const float* __restrict__ W11,
                      const float* __restrict__ b10, const float* __restrict__ b11,
                      const float* __restrict__ W20, const float* __restrict__ W21,
                      const float* __restrict__ b20, const float* __restrict__ b21,
                      float* o0, float* o1, int N, int nTiles)
{
    const float* in = blockIdx.y ? conv1 : conv0;
    const float* W1 = blockIdx.y ? W11 : W10;
    const float* b1 = blockIdx.y ? b11 : b10;
    const float* W2 = blockIdx.y ? W21 : W20;
    const float* b2 = blockIdx.y ? b21 : b20;
    float* out      = blockIdx.y ? o1  : o0;

    const int tid = threadIdx.x;
    const int l = tid & 63, w = tid >> 6;
    const int lr = l & 15, lk = l >> 4;
    const int wcol0 = w * 32;

    __shared__ unsigned short Ahi[64 * NF];
    __shared__ unsigned short Alo[64 * NF];

    short8 w1fr[4][2], w2fr[4][2];
    #pragma unroll
    for (int kb = 0; kb < 4; ++kb)
        #pragma unroll
        for (int cb = 0; cb < 2; ++cb) {
            const int col = wcol0 + cb * 16 + lr;
            #pragma unroll
            for (int j = 0; j < 8; ++j) {
                const size_t kk = (size_t)(kb * 32 + lk * 8 + j) * NF + col;
                w1fr[kb][cb][j] = (short)f2bf(W1[kk]);
                w2fr[kb][cb][j] = (short)f2bf(W2[kk]);
            }
        }
    const float b1c0 = b1[wcol0 + lr], b1c1 = b1[wcol0 + 16 + lr];
    const float b2c0 = b2[wcol0 + lr], b2c1 = b2[wcol0 + 16 + lr];

    for (int tile = blockIdx.x; tile < nTiles; tile += gridDim.x) {
        const int n0 = tile * 64;
        __syncthreads();
        #pragma unroll
        for (int s = 0; s < 32; ++s) {
            const int t = s * 256 + tid;
            const int row = t >> 7, cc = t & (NF - 1);
            const float v = (n0 + row < N) ? in[(size_t)(n0 + row) * NF + cc] : 0.f;
            const unsigned short hi = f2bf(v);
            const int idx = row * NF + (cc ^ ((row & 7) << 3));
            Ahi[idx] = hi;
            Alo[idx] = f2bf(v - bf2f(hi));
        }
        __syncthreads();

        f32x4 acc1[4][2] = {};
        #pragma unroll
        for (int rb = 0; rb < 4; ++rb) {
            short8 ah[4], al[4];
            #pragma unroll
            for (int kb = 0; kb < 4; ++kb) {
                const int e  = rb * 16 + lr;
                const int k0 = kb * 32 + lk * 8;
                const int idx = e * NF + (k0 ^ ((e & 7) << 3));
                ah[kb] = *reinterpret_cast<const short8*>(&Ahi[idx]);
                al[kb] = *reinterpret_cast<const short8*>(&Alo[idx]);
            }
            #pragma unroll
            for (int cb = 0; cb < 2; ++cb)
                #pragma unroll
                for (int kb = 0; kb < 4; ++kb) {
                    acc1[rb][cb] = __builtin_amdgcn_mfma_f32_16x16x32_bf16(
                        ah[kb], w1fr[kb][cb], acc1[rb][cb], 0, 0, 0);
                    acc1[rb][cb] = __builtin_amdgcn_mfma_f32_16x16x32_bf16(
                        al[kb], w1fr[kb][cb], acc1[rb][cb], 0, 0, 0);
                }
        }
        __syncthreads();

        #pragma unroll
        for (int rb = 0; rb < 4; ++rb)
            #pragma unroll
            for (int cb = 0; cb < 2; ++cb) {
                const int col = wcol0 + cb * 16 + lr;
                #pragma unroll
                for (int q = 0; q < 4; ++q) {
                    const int e = rb * 16 + lk * 4 + q;
                    const float hv = sspf(acc1[rb][cb][q] + (cb ? b1c1 : b1c0));
                    const unsigned short hi = f2bf(hv);
                    const int idx = e * NF + (col ^ ((e & 7) << 3));
                    Ahi[idx] = hi;
                    Alo[idx] = f2bf(hv - bf2f(hi));
                }
            }
        __syncthreads();

        f32x4 acc2[4][2] = {};
        #pragma unroll
        for (int rb = 0; rb < 4; ++rb) {
            short8 ah[4], al[4];
            #pragma unroll
            for (int kb = 0; kb < 4; ++kb) {
                const int e  = rb * 16 + lr;
                const int k0 = kb * 32 + lk * 8;
                const int idx = e * NF + (k0 ^ ((e & 7) << 3));
                ah[kb] = *reinterpret_cast<const short8*>(&Ahi[idx]);
                al[kb] = *reinterpret_cast<const short8*>(&Alo[idx]);
            }
            #pragma unroll
            for (int cb = 0; cb < 2; ++cb)
                #pragma unroll
                for (int kb = 0; kb < 4; ++kb) {
                    acc2[rb][cb] = __builtin_amdgcn_mfma_f32_16x16x32_bf16(
                        ah[kb], w2fr[kb][cb], acc2[rb][cb], 0, 0, 0);
                    acc2[rb][cb] = __builtin_amdgcn_mfma_f32_16x16x32_bf16(
                        al[kb], w2fr[kb][cb], acc2[rb][cb], 0, 0, 0);
                }
        }

        #pragma unroll
        for (int rb = 0; rb < 4; ++rb)
            #pragma unroll
            for (int cb = 0; cb < 2; ++cb) {
                const int col = wcol0 + cb * 16 + lr;
                #pragma unroll
                for (int q = 0; q < 4; ++q) {
                    const int n = n0 + rb * 16 + lk * 4 + q;
                    if (n < N)
                        out[(size_t)n * NF + col] = acc2[rb][cb][q] + (cb ? b2c1 : b2c0);
                }
            }
    }
}

extern "C" void kernel_launch(void* const* d_in, const int* in_sizes, int n_in,
                              void* d_out, int out_size, void* d_ws, size_t ws_size,
                              hipStream_t stream)
{
    const float* x    = (const float*)d_in[0];
    const float* y    = (const float*)d_in[1];
    const float* f_ij = (const float*)d_in[2];
    const float* rcut = (const float*)d_in[3];
    const int* idx_i  = (const int*)d_in[4];
    const int* idx_j  = (const int*)d_in[5];
    const float* W_in2f   = (const float*)d_in[6];
    const float* W_in2f_y = (const float*)d_in[7];
    const float* Wf1 = (const float*)d_in[8];
    const float* bf1 = (const float*)d_in[9];
    const float* Wf2 = (const float*)d_in[10];
    const float* bf2 = (const float*)d_in[11];
    const float* Wx1 = (const float*)d_in[12];
    const float* bx1 = (const float*)d_in[13];
    const float* Wx2 = (const float*)d_in[14];
    const float* bx2 = (const float*)d_in[15];
    const float* Wy1 = (const float*)d_in[16];
    const float* by1 = (const float*)d_in[17];
    const float* Wy2 = (const float*)d_in[18];
    const float* by2 = (const float*)d_in[19];

    const int N = in_sizes[0] / NF;
    const int E = in_sizes[4];

    unsigned short* xf = (unsigned short*)d_out;
    unsigned short* yf = xf + (size_t)N * NF;
    float* ox = (float*)d_out;
    float* oy = ox + (size_t)N * NF;

    float* conv_x = (float*)d_ws;
    float* conv_y = conv_x + (size_t)N * NF;

    const int nodeTiles = (N + 63) / 64;
    const int edgeTiles = (E + 63) / 64;

    proj_mfma_kernel<<<dim3(1024, 2), 256, 0, stream>>>(
        x, y, W_in2f, W_in2f_y, xf, yf, conv_x, conv_y, N, nodeTiles);

    edge_mfma_kernel<<<dim3(1024), 512, 0, stream>>>(
        f_ij, rcut, idx_i, idx_j, Wf1, bf1, Wf2, bf2, xf, yf,
        conv_x, conv_y, E, edgeTiles);

    out_fused_kernel<<<dim3(1024, 2), 256, 0, stream>>>(
        conv_x, conv_y, Wx1, Wy1, bx1, by1, Wx2, Wy2, bx2, by2,
        ox, oy, N, nodeTiles);
}